// Round 2
// baseline (846.917 us; speedup 1.0000x reference)
//
#include <hip/hip_runtime.h>

#define Bn 256
#define Sn 1024
#define Tn 64

__device__ __forceinline__ float wave_max_f(float v) {
  #pragma unroll
  for (int o = 32; o > 0; o >>= 1) v = fmaxf(v, __shfl_xor(v, o, 64));
  return v;
}
__device__ __forceinline__ float wave_sum_f(float v) {
  #pragma unroll
  for (int o = 32; o > 0; o >>= 1) v += __shfl_xor(v, o, 64);
  return v;
}

// Blocks 0..255: forward algorithm, linear domain (one wave per batch).
// Blocks 256..511: gold path score.
__global__ __launch_bounds__(64, 1) void crf_fwd_gold(
    const float* __restrict__ em, const int* __restrict__ tags,
    const int* __restrict__ mask, const float* __restrict__ trans,
    const float* __restrict__ startt, const float* __restrict__ endt,
    float* __restrict__ ws) {
  const int bid = blockIdx.x;
  const int j = threadIdx.x;

  if (bid < Bn) {
    const int b = bid;
    const float* emb = em + (size_t)b * Sn * Tn;
    const int* mk = mask + (size_t)b * Sn;

    // F[i][j] = exp(trans[i][j]); lane j holds column j. Fully unrolled
    // constant-index float4 array -> must stay in 64 VGPRs (check VGPR_Count!).
    float4 F4[16];
    #pragma unroll
    for (int i = 0; i < 16; ++i) {
      F4[i].x = __expf(trans[(4 * i + 0) * Tn + j]);
      F4[i].y = __expf(trans[(4 * i + 1) * Tn + j]);
      F4[i].z = __expf(trans[(4 * i + 2) * Tn + j]);
      F4[i].w = __expf(trans[(4 * i + 3) * Tn + j]);
    }

    // v = exp(alpha - C), C uniform across lanes.
    float alpha0 = startt[j] + emb[j];
    float C = wave_max_f(alpha0);
    float v = __expf(alpha0 - C);

    __shared__ __align__(16) float pbuf[2][Tn];

    // mask chunk pipeline: lane j holds mk[c*64 + j]
    int mchunk = mk[j];
    int mnext = mk[64 + j];

    // emission pipeline: e1,e2 = exp'd (steps t, t+1); r3,r4 = raw (t+2, t+3)
    float e1 = __expf(emb[1 * Tn + j]);
    float e2 = __expf(emb[2 * Tn + j]);
    float r3 = emb[3 * Tn + j];
    float r4 = emb[4 * Tn + j];

    for (int t = 1; t < Sn; ++t) {
      if ((t & 63) == 0) {  // uniform branch, every 64 steps
        mchunk = mnext;
        int c2 = (t >> 6) + 1;
        c2 = (c2 < (Sn / 64)) ? c2 : (Sn / 64) - 1;
        mnext = mk[c2 * 64 + j];
      }
      // rotate emission pipeline; exp applied 2 iters after load (vmcnt hidden)
      float ee = e1;
      e1 = e2;
      e2 = __expf(r3);
      r3 = r4;
      int tn = t + 4;
      tn = (tn < Sn) ? tn : (Sn - 1);
      r4 = emb[(size_t)tn * Tn + j];

      // broadcast v across lanes via LDS (no __syncthreads: single wave,
      // DS ops execute in order; wave_barrier pins compiler ordering)
      ((volatile float*)pbuf[t & 1])[j] = v;
      __builtin_amdgcn_wave_barrier();
      const float4* pb = (const float4*)pbuf[t & 1];
      float a0 = 0.f, a1 = 0.f, a2 = 0.f, a3 = 0.f;
      #pragma unroll
      for (int i = 0; i < 16; ++i) {
        float4 pv = pb[i];  // ds_read_b128, same-address broadcast
        a0 = fmaf(pv.x, F4[i].x, a0);
        a1 = fmaf(pv.y, F4[i].y, a1);
        a2 = fmaf(pv.z, F4[i].z, a2);
        a3 = fmaf(pv.w, F4[i].w, a3);
      }
      float s = (a0 + a1) + (a2 + a3);
      float vn = s * ee;
      int mcur = __shfl(mchunk, t & 63, 64);
      v = (mcur != 0) ? vn : v;

      if ((t & 7) == 0) {  // renorm by lane0 (uniform, any positive scale ok)
        float r = __shfl(v, 0, 64);
        r = fmaxf(r, 1e-35f);
        v *= __builtin_amdgcn_rcpf(r);
        C += __logf(r);
      }
    }

    // log_Z = C + log(sum_j v_j * exp(end_j))
    float w = v * __expf(endt[j]);
    float ss = wave_sum_f(w);
    if (j == 0) ws[b] = C + __logf(ss);
  } else {
    // ---------------- gold score ----------------
    const int b = bid - Bn;
    const float* emb = em + (size_t)b * Sn * Tn;
    const int* tg = tags + (size_t)b * Sn;
    const int* mk = mask + (size_t)b * Sn;

    float acc = 0.f;
    int msum = 0;
    for (int t = j; t < Sn; t += 64) {
      int mv = mk[t];
      msum += mv;
      if (t >= 1 && mv != 0) {
        int tp = tg[t - 1], tc = tg[t];
        acc += trans[tp * Tn + tc] + emb[(size_t)t * Tn + tc];
      }
    }
    #pragma unroll
    for (int o = 32; o > 0; o >>= 1) {
      acc += __shfl_xor(acc, o, 64);
      msum += __shfl_xor(msum, o, 64);
    }
    if (j == 0) {
      int t0 = tg[0];
      float sc = startt[t0] + emb[t0] + acc;
      int last = msum - 1;
      sc += endt[tg[last]];
      ws[Bn + b] = sc;
    }
  }
}

__global__ __launch_bounds__(256) void crf_reduce(const float* __restrict__ ws,
                                                  float* __restrict__ out) {
  int i = threadIdx.x;  // 256 threads = 4 waves
  float v = ws[i] - ws[Bn + i];
  #pragma unroll
  for (int o = 32; o > 0; o >>= 1) v += __shfl_xor(v, o, 64);
  __shared__ float sb[4];
  if ((i & 63) == 0) sb[i >> 6] = v;
  __syncthreads();
  if (i == 0) out[0] = (sb[0] + sb[1] + sb[2] + sb[3]) * (1.0f / Bn);
}

extern "C" void kernel_launch(void* const* d_in, const int* in_sizes, int n_in,
                              void* d_out, int out_size, void* d_ws, size_t ws_size,
                              hipStream_t stream) {
  const float* em     = (const float*)d_in[0];
  const int*   tags   = (const int*)d_in[1];
  const int*   mask   = (const int*)d_in[2];
  const float* trans  = (const float*)d_in[3];
  const float* startt = (const float*)d_in[4];
  const float* endt   = (const float*)d_in[5];
  float* ws  = (float*)d_ws;
  float* out = (float*)d_out;

  crf_fwd_gold<<<2 * Bn, Tn, 0, stream>>>(em, tags, mask, trans, startt, endt, ws);
  crf_reduce<<<1, 256, 0, stream>>>(ws, out);
}